// Round 9
// baseline (406.008 us; speedup 1.0000x reference)
//
#include <hip/hip_runtime.h>
#include <hip/hip_bf16.h>

// Problem dims (fixed by setup_inputs): B=4, S=2048, DIN=4096, DOUT=4096, GS=32
#define DIN   4096
#define DOUT  4096
#define MROWS 8192            // B*S
#define GSIZE 32
#define NGPR  (DIN / GSIZE)   // groups per row = 128
#define NG_ACT (MROWS * NGPR) // 1048576
#define NG_W   (DOUT * NGPR)  // 524288

typedef __bf16 bf16_t;
typedef __attribute__((ext_vector_type(8))) __bf16 bf16x8;
typedef __attribute__((ext_vector_type(4))) float f32x4;

typedef const __attribute__((address_space(1))) void* gptr_t;
typedef __attribute__((address_space(3))) void* lptr_t;

// floor(log2(max(a,1))) grid rounding to the FP4 E2M1 set {0,±0.5,1,1.5,2,3,4,6}
__device__ __forceinline__ float fp4_round(float y) {
  float a  = __builtin_fabsf(y);
  float am = fmaxf(a, 1.0f);
  int   e  = (int)((__float_as_uint(am) >> 23) & 255u) - 127;  // floor(log2(max(a,1)))
  float step = __uint_as_float((unsigned)(e - 1 + 127) << 23); // 2^(e-1): 0.5, 1, 2
  float q = rintf(a / step) * step;  // RNE, matches jnp.round
  q = fminf(q, 6.0f);
  return copysignf(q, y);
}

// ---------------- activation quant: one thread per group of 32 ----------------
__global__ __launch_bounds__(256) void act_quant(const float* __restrict__ x,
                                                 bf16_t* __restrict__ xq,
                                                 float* __restrict__ exps_out) {
  int g = blockIdx.x * 256 + threadIdx.x;
  const float4* xp = reinterpret_cast<const float4*>(x) + (size_t)g * 8;
  float v[32];
  float amax = 0.f;
#pragma unroll
  for (int i = 0; i < 8; ++i) {
    float4 t = xp[i];
    v[4*i+0] = t.x; v[4*i+1] = t.y; v[4*i+2] = t.z; v[4*i+3] = t.w;
    amax = fmaxf(amax, fmaxf(fmaxf(__builtin_fabsf(t.x), __builtin_fabsf(t.y)),
                             fmaxf(__builtin_fabsf(t.z), __builtin_fabsf(t.w))));
  }
  float exps = 0.f;
  if (amax > 0.f) {
    float am = fmaxf(amax, 1e-30f);
    exps = (float)((int)((__float_as_uint(am) >> 23) & 255u) - 129);  // floor(log2)-2
  }
  float scale = __uint_as_float((unsigned)((int)exps + 127) << 23);   // 2^exps (exact)
  float inv   = __uint_as_float((unsigned)(127 - (int)exps) << 23);   // 2^-exps (exact)
  bf16x8 hv[4];
#pragma unroll
  for (int i = 0; i < 32; ++i) {
    float q = fp4_round(v[i] * inv) * scale;  // exact: pow2 scaling both ways
    hv[i >> 3][i & 7] = (bf16_t)q;            // exact in bf16 (<=2 mantissa bits * 2^e)
  }
  bf16x8* dst = reinterpret_cast<bf16x8*>(xq + (size_t)g * 32);
#pragma unroll
  for (int i = 0; i < 4; ++i) dst[i] = hv[i];
  exps_out[g] = exps;
}

// ---------------- weight quant with (1+eps_eff) scale ----------------
__global__ __launch_bounds__(256) void w_quant(const float* __restrict__ w,
                                               const float* __restrict__ eps,
                                               const float* __restrict__ adv,
                                               bf16_t* __restrict__ wq,
                                               float* __restrict__ eps_eff_out,
                                               float* __restrict__ w_exps_out) {
  int g = blockIdx.x * 256 + threadIdx.x;
  float ee = eps[g] + adv[g];
  eps_eff_out[g] = ee;
  const float4* wp = reinterpret_cast<const float4*>(w) + (size_t)g * 8;
  float v[32];
  float amax = 0.f;
#pragma unroll
  for (int i = 0; i < 8; ++i) {
    float4 t = wp[i];
    v[4*i+0] = t.x; v[4*i+1] = t.y; v[4*i+2] = t.z; v[4*i+3] = t.w;
    amax = fmaxf(amax, fmaxf(fmaxf(__builtin_fabsf(t.x), __builtin_fabsf(t.y)),
                             fmaxf(__builtin_fabsf(t.z), __builtin_fabsf(t.w))));
  }
  float exps = 0.f;
  if (amax > 0.f) {
    float am = fmaxf(amax, 1e-30f);
    exps = (float)((int)((__float_as_uint(am) >> 23) & 255u) - 129);
  }
  w_exps_out[g] = exps;
  float p2   = __uint_as_float((unsigned)((int)exps + 127) << 23);  // 2^exps
  float scale = p2 * (1.0f + ee);                                   // matches reference order
  bf16x8 hv[4];
#pragma unroll
  for (int i = 0; i < 32; ++i) {
    float q = fp4_round(v[i] / scale) * scale;  // IEEE div, matches reference
    hv[i >> 3][i & 7] = (bf16_t)q;              // only bf16-rounding error source
  }
  bf16x8* dst = reinterpret_cast<bf16x8*>(wq + (size_t)g * 32);
#pragma unroll
  for (int i = 0; i < 4; ++i) dst[i] = hv[i];
}

// ---------------- bf16 GEMM: C[M,N] = A[M,K] * B[N,K]^T + bias ----------------
// r9: CROSS-BLOCK TLP structure. 128x128 tile, BK=32, 4 waves (2x2, per-wave
// 64x64, acc=64 regs), TRIPLE-buffered 48 KiB LDS -> 3 blocks/CU (12 waves/CU).
// Rationale: r4-r8 (256^2, 1 block/CU, 8 barriers/K-tile) pinned at 37% MfmaUtil
// because lockstep barriers serialize the CU's LDS-read window (~2300cyc/K-tile)
// and MFMA window (~2480cyc). Independent blocks are never barrier-coupled ->
// one block's MFMA covers another's LDS/stage stalls (m114 mechanism).
// Per K-step (ONE barrier): STG(j+2 -> buf[(j+2)%3]) | 8 ds_read_b128 from
// buf[j%3] | 16 MFMA | sched_barrier+lgkm(0) (pins read retirement pre-barrier;
// rule #18) | counted vmcnt(4) (waits loads issued TWO K-steps ago ~= full HBM
// latency of cover; never 0 in steady state) | s_barrier | sched_barrier.
// Buffer safety: iter j stages buf[(j+2)%3], last read at iter j-1 (reads
// retired before that iter's lgkm(0)+barrier). Iter j+1 stages buf[j%3]; iter
// j's reads of it are pinned pre-barrier by the lgkm(0)+sched_barrier fence.
// LDS swizzle for 64B rows (BK=32): phys slot(row, chunk c) = c ^ ((row>>2)&3)
// -> worst-case 2-way read aliasing (free, m136). Staged via pre-swizzled
// global source col chunk (l&3)^((l>>4)&3) with linear gload_lds dest (involution
// on both sides, rule #21).
__global__ __launch_bounds__(256, 3) void gemm_bt(const bf16_t* __restrict__ A,
                                                  const bf16_t* __restrict__ B,
                                                  const float* __restrict__ bias,
                                                  float* __restrict__ C) {
  __shared__ bf16_t sA[3 * 4096];   // 3 bufs x 128 rows x 32 cols
  __shared__ bf16_t sB[3 * 4096];
  const int tid  = threadIdx.x;
  const int wave = tid >> 6;   // 0..3
  const int lane = tid & 63;

  // T1: bijective XCD swizzle (2048 blocks, 2048 % 8 == 0)
  const int swz = (blockIdx.x & 7) * 256 + (blockIdx.x >> 3);
  const int tm0 = (swz >> 5) * 128;   // 64 M-tiles
  const int tn0 = (swz & 31) * 128;   // 32 N-tiles

  const int wr = wave >> 1;   // 0..1 : M-half (64 rows)
  const int wc = wave & 1;    // 0..1 : N-half (64 cols)

  // ---- staging: per wave 4 gload_lds (A rows [w*32,+32), B rows [w*32,+32)) ----
  const int lr = lane >> 2;                               // 0..15
  const int lc = ((lane & 3) ^ ((lane >> 4) & 3)) * 8;    // pre-swizzled src chunk
  const bf16_t* gA = A + (size_t)(tm0 + wave * 32 + lr) * DIN + lc;
  const bf16_t* gB = B + (size_t)(tn0 + wave * 32 + lr) * DIN + lc;
  const int dst0 = wave * 1024;   // elems within one buf (32 rows x 32 cols)

#define STG(kt, bf) do {                                                            \
    const bf16_t* a_ = gA + (size_t)(kt) * 32;                                      \
    const bf16_t* b_ = gB + (size_t)(kt) * 32;                                      \
    __builtin_amdgcn_global_load_lds((gptr_t)a_,                                    \
        (lptr_t)(sA + (bf) * 4096 + dst0), 16, 0, 0);                               \
    __builtin_amdgcn_global_load_lds((gptr_t)(a_ + (size_t)16 * DIN),               \
        (lptr_t)(sA + (bf) * 4096 + dst0 + 512), 16, 0, 0);                         \
    __builtin_amdgcn_global_load_lds((gptr_t)b_,                                    \
        (lptr_t)(sB + (bf) * 4096 + dst0), 16, 0, 0);                               \
    __builtin_amdgcn_global_load_lds((gptr_t)(b_ + (size_t)16 * DIN),               \
        (lptr_t)(sB + (bf) * 4096 + dst0 + 512), 16, 0, 0);                         \
  } while (0)

  // ---- fragment read offsets (bytes): byte = row*64 + 16*((lane>>4) ^ ((row>>2)&3))
  // row = wg*64 + mf*16 + (lane&15) -> ((row>>2)&3) == ((lane>>2)&3)
  const int slot  = (((lane >> 4) ^ ((lane >> 2) & 3)) << 4);
  const int apart = (wr * 64 + (lane & 15)) * 64 + slot;
  const int bpart = (wc * 64 + (lane & 15)) * 64 + slot;

  f32x4 acc[4][4] = {};

  // ---- prologue: tiles 0,1 staged; tile 0 landed, tile 1 in flight ----
  STG(0, 0); STG(1, 1);
  asm volatile("s_waitcnt vmcnt(4)");
  __builtin_amdgcn_s_barrier();
  __builtin_amdgcn_sched_barrier(0);

  for (int j = 0; j < 128; ++j) {
    if (j + 2 < 128) STG(j + 2, (j + 2) % 3);   // buf free since iter j-1
    const char* bA = (const char*)sA + (j % 3) * 8192;
    const char* bB = (const char*)sB + (j % 3) * 8192;
    bf16x8 a[4], b[4];
#pragma unroll
    for (int m = 0; m < 4; ++m)
      a[m] = *reinterpret_cast<const bf16x8*>(bA + apart + m * 1024);
#pragma unroll
    for (int n = 0; n < 4; ++n)
      b[n] = *reinterpret_cast<const bf16x8*>(bB + bpart + n * 1024);
#pragma unroll
    for (int m = 0; m < 4; ++m)
#pragma unroll
      for (int n = 0; n < 4; ++n)
        acc[m][n] = __builtin_amdgcn_mfma_f32_16x16x32_bf16(a[m], b[n], acc[m][n], 0, 0, 0);
    __builtin_amdgcn_sched_barrier(0);          // nothing above may sink past here
    asm volatile("s_waitcnt lgkmcnt(0)");       // reads serviced before barrier
    if (j < 126) {
      asm volatile("s_waitcnt vmcnt(4)");       // tile j+1 landed; j+2 in flight
    } else {
      asm volatile("s_waitcnt vmcnt(0)");       // tail drain
    }
    __builtin_amdgcn_s_barrier();
    __builtin_amdgcn_sched_barrier(0);          // next-iter reads can't hoist
  }

  // ---- epilogue: D row=(lane>>4)*4+reg, col=lane&15 (m89-verified) ----
  const int r0 = tm0 + wr * 64 + ((lane >> 4) << 2);
  const int c0 = tn0 + wc * 64 + (lane & 15);
#pragma unroll
  for (int n = 0; n < 4; ++n) {
    float bv = bias[c0 + n * 16];
#pragma unroll
    for (int m = 0; m < 4; ++m) {
#pragma unroll
      for (int jj = 0; jj < 4; ++jj) {
        C[(size_t)(r0 + m * 16 + jj) * DOUT + c0 + n * 16] = acc[m][n][jj] + bv;
      }
    }
  }
#undef STG
}

extern "C" void kernel_launch(void* const* d_in, const int* in_sizes, int n_in,
                              void* d_out, int out_size, void* d_ws, size_t ws_size,
                              hipStream_t stream) {
  const float* x    = (const float*)d_in[0];  // (4,2048,4096)
  const float* adv  = (const float*)d_in[1];  // (4096,128)
  const float* wfp  = (const float*)d_in[2];  // (4096,4096)
  const float* bias = (const float*)d_in[3];  // (4096,)
  const float* eps  = (const float*)d_in[4];  // (4096,128)

  float* out      = (float*)d_out;                    // 33554432
  float* eps_eff  = out + (size_t)MROWS * DOUT;       // 524288
  float* w_exps   = eps_eff + NG_W;                   // 524288
  float* act_exps = w_exps + NG_W;                    // 1048576

  bf16_t* xq = (bf16_t*)d_ws;                          // 67.1 MB
  bf16_t* wq = (bf16_t*)d_ws + (size_t)MROWS * DIN;    // +33.6 MB

  act_quant<<<NG_ACT / 256, 256, 0, stream>>>(x, xq, act_exps);
  w_quant<<<NG_W / 256, 256, 0, stream>>>(wfp, eps, adv, wq, eps_eff, w_exps);
  gemm_bt<<<dim3((MROWS / 128) * (DOUT / 128)), 256, 0, stream>>>(xq, wq, bias, out);
}